// Round 1
// baseline (1660.196 us; speedup 1.0000x reference)
//
#include <hip/hip_runtime.h>
#include <math.h>

#define TMASK 524287   // 2^19 - 1
#define PM0 455773     // 73856093 % 2^19
#define PM1 475295     // 19349663 % 2^19
#define PM2 130999     // 83492791 % 2^19

struct Params {
  const float* x; const float* freq; const float* tables;
  const float* W0; const float* b0; const float* W1; const float* b1;
  const float* W2; const float* b2; const float* W3; const float* b3;
  const float* e_w1; const float* e_b1; const float* e_w2; const float* e_b2;
  const float* e_g;  const float* e_be;
  const float* m_w1; const float* m_b1; const float* m_w2; const float* m_b2;
  const float* m_g;  const float* m_be;
  const float* p_w1; const float* p_b1; const float* p_w2; const float* p_b2;
  const float* mat_w1; const float* mat_b1; const float* mat_w2; const float* mat_b2;
  const float* s_w1; const float* s_b1; const float* s_w2; const float* s_b2;
  float* out;
  int N;
  int res[16];
};

__device__ __forceinline__ float sigmoid_(float v){ return 1.f/(1.f + expf(-v)); }

// acc[16] += in[p0+p, koff..koff+K) @ W[koff.., c]; W leading dim 128, in leading dim LDIN
template<int LDIN>
__device__ __forceinline__ void gemm16(float acc[16], const float* __restrict__ W,
                                       int c, int koff, int K,
                                       const float* in, int p0)
{
  const float* wp = W + (size_t)koff*128 + c;
  const float* fpb = in + p0*LDIN;
  for (int kc = 0; kc < K; kc += 4) {
    const float w0 = wp[0];
    const float w1 = wp[128];
    const float w2 = wp[256];
    const float w3 = wp[384];
    wp += 512;
    #pragma unroll
    for (int p = 0; p < 16; ++p) {
      const float4 f = *(const float4*)(fpb + p*LDIN + kc);
      acc[p] = fmaf(f.x, w0, acc[p]);
      acc[p] = fmaf(f.y, w1, acc[p]);
      acc[p] = fmaf(f.z, w2, acc[p]);
      acc[p] = fmaf(f.w, w3, acc[p]);
    }
  }
}

// head first layer: h[32,128] @ W[128,OC] + b -> hb[32, stride 65] (raw, no relu)
template<int OC>
__device__ __forceinline__ void head_l1(int tid, const float* __restrict__ W,
                                        const float* __restrict__ bias,
                                        const float* h, float* hb)
{
  constexpr int NP = (32*OC)/256;     // points per thread: OC=64 -> 8, OC=32 -> 4
  const int c  = tid & (OC-1);
  const int p0 = (tid/OC) * NP;
  float acc[NP];
  const float bv = bias[c];
  #pragma unroll
  for (int i=0;i<NP;i++) acc[i]=bv;
  const float* wp = W + c;
  const float* fpb = h + p0*128;
  for (int kc = 0; kc < 128; kc += 4) {
    const float w0 = wp[0];
    const float w1 = wp[OC];
    const float w2 = wp[2*OC];
    const float w3 = wp[3*OC];
    wp += 4*OC;
    #pragma unroll
    for (int p=0;p<NP;p++){
      const float4 f = *(const float4*)(fpb + p*128 + kc);
      acc[p] = fmaf(f.x,w0, fmaf(f.y,w1, fmaf(f.z,w2, fmaf(f.w,w3, acc[p]))));
    }
  }
  #pragma unroll
  for (int p=0;p<NP;p++) hb[(p0+p)*65 + c] = acc[p];
}

// head second layer: optional LN (pre-relu), relu, @ W2[K2,OC2] + b2, optional tanh
template<int OC2, int K2, bool LN, bool TANH>
__device__ __forceinline__ void head_l2(int tid, const float* hb,
                                        const float* __restrict__ g, const float* __restrict__ be,
                                        const float* __restrict__ W2, const float* __restrict__ b2,
                                        float* res2, int slot,
                                        const float* mean, const float* inv)
{
  if (tid < 32*OC2) {
    const int p = tid / OC2;
    const int j = tid - p*OC2;
    float mn = 0.f, iv = 0.f;
    if constexpr (LN) { mn = mean[p]; iv = inv[p]; }
    float acc = b2[j];
    const float* row = hb + p*65;
    #pragma unroll 4
    for (int k=0;k<K2;k++){
      float v = row[k];
      if constexpr (LN) v = (v - mn)*iv*g[k] + be[k];
      v = fmaxf(v, 0.f);
      acc = fmaf(v, W2[k*OC2 + j], acc);
    }
    if constexpr (TANH) acc = tanhf(acc);
    res2[p*20 + slot + j] = acc;
  }
}

__global__ __launch_bounds__(256, 4)
void em_nerf_fused(Params P)
{
  __shared__ __align__(16) float feat[32*52];   // 1664 floats
  __shared__ __align__(16) float hA[32*128];    // 4096 floats
  __shared__ __align__(16) float hB[32*128];    // 4096 floats
  __shared__ int s_res[16];

  float* headbuf = hA;            // 32*65 = 2080 (alias: hA dead when heads run)
  float* res2    = hA + 2080;     // 32*20 = 640
  float* lnmean  = hA + 2720;     // 32
  float* lninv   = hA + 2752;     // 32

  const int tid = threadIdx.x;
  if (tid == 0) {
    #pragma unroll
    for (int i=0;i<16;i++) s_res[i] = P.res[i];
  }
  __syncthreads();

  // ---------------- encode: hash (32 feats) + freq (20 feats) -> feat[32][52]
  {
    const int p = tid & 31;
    const int g = tid >> 5;            // 0..7, two levels each
    int gp = blockIdx.x*32 + p;
    if (gp >= P.N) gp = P.N - 1;
    float xs0 = fminf(fmaxf(P.x[gp*3+0], 0.f), 1.f);
    float xs1 = fminf(fmaxf(P.x[gp*3+1], 0.f), 1.f);
    float xs2 = fminf(fmaxf(P.x[gp*3+2], 0.f), 1.f);
    #pragma unroll
    for (int j=0;j<2;j++){
      const int l = g*2 + j;
      const int res = s_res[l];
      const float rf = (float)(res-1);
      const float s0 = xs0*rf, s1 = xs1*rf, s2 = xs2*rf;
      int f0i = (int)s0; if (f0i > res-1) f0i = res-1;
      int f1i = (int)s1; if (f1i > res-1) f1i = res-1;
      int f2i = (int)s2; if (f2i > res-1) f2i = res-1;
      const float w0 = s0 - (float)f0i;
      const float w1 = s1 - (float)f1i;
      const float w2 = s2 - (float)f2i;
      int c0i = f0i+1; if (c0i > res-1) c0i = res-1;
      int c1i = f1i+1; if (c1i > res-1) c1i = res-1;
      int c2i = f2i+1; if (c2i > res-1) c2i = res-1;
      const int hx0 = (f0i*PM0) & TMASK, hx1 = (c0i*PM0) & TMASK;
      const int hy0 = (f1i*PM1) & TMASK, hy1 = (c1i*PM1) & TMASK;
      const int hz0 = (f2i*PM2) & TMASK, hz1 = (c2i*PM2) & TMASK;
      const float* tp = P.tables + ((size_t)l << 20);  // l * TABLE * 2
      float a0 = 0.f, a1 = 0.f;
      #pragma unroll
      for (int cn=0; cn<8; ++cn){
        const int bx = (cn>>2)&1, by=(cn>>1)&1, bz = cn&1;
        const int hh = ((bx?hx1:hx0) + (by?hy1:hy0) + (bz?hz1:hz0)) & TMASK;
        const float cw = (bx?w0:1.f-w0)*(by?w1:1.f-w1)*(bz?w2:1.f-w2);
        const float2 tv = *(const float2*)(tp + 2*hh);
        a0 = fmaf(cw, tv.x, a0);
        a1 = fmaf(cw, tv.y, a1);
      }
      feat[p*52 + 2*l]   = a0;
      feat[p*52 + 2*l+1] = a1;
    }
    if (g == 0) {
      float fr = P.freq[gp];
      fr = fminf(fmaxf(fr, 1e6f), 1e12f);
      const float nf = (log10f(fr) - 6.f) * (1.f/6.f);
      float a = 3.14159274101257324f * nf;   // (float)M_PI; *2 per band is exact
      #pragma unroll
      for (int i=0;i<10;i++){
        feat[p*52 + 32 + 2*i] = sinf(a);
        feat[p*52 + 33 + 2*i] = cosf(a);
        a = a * 2.f;
      }
    }
  }
  __syncthreads();

  const int c  = tid & 127;
  const int p0 = (tid >> 7) * 16;

  // ---------------- trunk layer 0: feat(52) -> hA
  {
    float acc[16]; const float bv = P.b0[c];
    #pragma unroll
    for (int i=0;i<16;i++) acc[i]=bv;
    gemm16<52>(acc, P.W0, c, 0, 52, feat, p0);
    #pragma unroll
    for (int i=0;i<16;i++) hA[(p0+i)*128 + c] = fmaxf(acc[i], 0.f);
  }
  __syncthreads();

  // ---------------- trunk layer 1: hA(128) -> hB
  {
    float acc[16]; const float bv = P.b1[c];
    #pragma unroll
    for (int i=0;i<16;i++) acc[i]=bv;
    gemm16<128>(acc, P.W1, c, 0, 128, hA, p0);
    #pragma unroll
    for (int i=0;i<16;i++) hB[(p0+i)*128 + c] = fmaxf(acc[i], 0.f);
  }
  __syncthreads();

  // ---------------- trunk layer 2 (skip concat): [hB(128) | feat(52)] -> hA
  {
    float acc[16]; const float bv = P.b2[c];
    #pragma unroll
    for (int i=0;i<16;i++) acc[i]=bv;
    gemm16<128>(acc, P.W2, c, 0,  128, hB,   p0);
    gemm16<52> (acc, P.W2, c, 128, 52, feat, p0);
    #pragma unroll
    for (int i=0;i<16;i++) hA[(p0+i)*128 + c] = fmaxf(acc[i], 0.f);
  }
  __syncthreads();

  // ---------------- trunk layer 3: hA(128) -> hB  (this is `h` for the heads)
  {
    float acc[16]; const float bv = P.b3[c];
    #pragma unroll
    for (int i=0;i<16;i++) acc[i]=bv;
    gemm16<128>(acc, P.W3, c, 0, 128, hA, p0);
    #pragma unroll
    for (int i=0;i<16;i++) hB[(p0+i)*128 + c] = fmaxf(acc[i], 0.f);
  }
  __syncthreads();

  // ---------------- E head (LN + tanh), slots 0..2
  head_l1<64>(tid, P.e_w1, P.e_b1, hB, headbuf);
  __syncthreads();
  if (tid < 32) {
    const float* row = headbuf + tid*65;
    float s = 0.f;
    for (int k=0;k<64;k++) s += row[k];
    const float m = s * (1.f/64.f);
    float v = 0.f;
    for (int k=0;k<64;k++){ const float d = row[k]-m; v = fmaf(d,d,v); }
    v *= (1.f/64.f);
    lnmean[tid] = m; lninv[tid] = 1.f/sqrtf(v + 1e-5f);
  }
  __syncthreads();
  head_l2<3,64,true,true>(tid, headbuf, P.e_g, P.e_be, P.e_w2, P.e_b2, res2, 0, lnmean, lninv);
  __syncthreads();

  // ---------------- B head (LN + tanh), slots 3..5
  head_l1<64>(tid, P.m_w1, P.m_b1, hB, headbuf);
  __syncthreads();
  if (tid < 32) {
    const float* row = headbuf + tid*65;
    float s = 0.f;
    for (int k=0;k<64;k++) s += row[k];
    const float m = s * (1.f/64.f);
    float v = 0.f;
    for (int k=0;k<64;k++){ const float d = row[k]-m; v = fmaf(d,d,v); }
    v *= (1.f/64.f);
    lnmean[tid] = m; lninv[tid] = 1.f/sqrtf(v + 1e-5f);
  }
  __syncthreads();
  head_l2<3,64,true,true>(tid, headbuf, P.m_g, P.m_be, P.m_w2, P.m_b2, res2, 3, lnmean, lninv);
  __syncthreads();

  // ---------------- phases head (32 hidden), slots 6..11
  head_l1<32>(tid, P.p_w1, P.p_b1, hB, headbuf);
  __syncthreads();
  head_l2<6,32,false,false>(tid, headbuf, nullptr, nullptr, P.p_w2, P.p_b2, res2, 6, nullptr, nullptr);
  __syncthreads();

  // ---------------- material head, slots 12..14
  head_l1<64>(tid, P.mat_w1, P.mat_b1, hB, headbuf);
  __syncthreads();
  head_l2<3,64,false,false>(tid, headbuf, nullptr, nullptr, P.mat_w2, P.mat_b2, res2, 12, nullptr, nullptr);
  __syncthreads();

  // ---------------- source head, slots 15..18
  head_l1<64>(tid, P.s_w1, P.s_b1, hB, headbuf);
  __syncthreads();
  head_l2<4,64,false,false>(tid, headbuf, nullptr, nullptr, P.s_w2, P.s_b2, res2, 15, nullptr, nullptr);
  __syncthreads();

  // ---------------- final packing (TIME=0 -> cos(phases))
  if (tid < 32) {
    const int gp = blockIdx.x*32 + tid;
    if (gp < P.N) {
      const float* r = res2 + tid*20;
      float* o = P.out + (size_t)gp*13;
      o[0] = r[0]*cosf(r[6]);
      o[1] = r[1]*cosf(r[7]);
      o[2] = r[2]*cosf(r[8]);
      o[3] = r[3]*cosf(r[9]);
      o[4] = r[4]*cosf(r[10]);
      o[5] = r[5]*cosf(r[11]);
      o[6] = 1.f + sigmoid_(r[12])*10.f;
      o[7] = 1.f + sigmoid_(r[13])*2.f;
      o[8] = sigmoid_(r[14])*0.01f;
      o[9]  = r[15];
      o[10] = r[16];
      o[11] = r[17];
      o[12] = r[18];
    }
  }
}

extern "C" void kernel_launch(void* const* d_in, const int* in_sizes, int n_in,
                              void* d_out, int out_size, void* d_ws, size_t ws_size,
                              hipStream_t stream) {
  (void)d_ws; (void)ws_size; (void)n_in; (void)out_size;
  const float** in = (const float**)d_in;
  Params P;
  P.x = in[0]; P.freq = in[1]; P.tables = in[2];
  P.W0 = in[3];  P.b0 = in[4];  P.W1 = in[5];  P.b1 = in[6];
  P.W2 = in[7];  P.b2 = in[8];  P.W3 = in[9];  P.b3 = in[10];
  P.e_w1 = in[11]; P.e_b1 = in[12]; P.e_w2 = in[13]; P.e_b2 = in[14];
  P.m_w1 = in[15]; P.m_b1 = in[16]; P.m_w2 = in[17]; P.m_b2 = in[18];
  P.p_w1 = in[19]; P.p_b1 = in[20]; P.p_w2 = in[21]; P.p_b2 = in[22];
  P.mat_w1 = in[23]; P.mat_b1 = in[24]; P.mat_w2 = in[25]; P.mat_b2 = in[26];
  P.s_w1 = in[27]; P.s_b1 = in[28]; P.s_w2 = in[29]; P.s_b2 = in[30];
  P.e_g = in[31]; P.e_be = in[32]; P.m_g = in[33]; P.m_be = in[34];
  P.out = (float*)d_out;
  P.N = in_sizes[0] / 3;

  // Replicate Python's module-level _RES computation bit-for-bit (same libm):
  // _B = exp((log(512)-log(16))/15); res[l] = min(int(16 * _B**l), 512)
  const double B = exp((log(512.0) - log(16.0)) / 15.0);
  for (int l = 0; l < 16; ++l) {
    double r = 16.0 * pow(B, (double)l);
    int ri = (int)r;               // truncation, same as Python int()
    if (ri > 512) ri = 512;
    P.res[l] = ri;
  }

  const int blocks = (P.N + 31) / 32;
  hipLaunchKernelGGL(em_nerf_fused, dim3(blocks), dim3(256), 0, stream, P);
}

// Round 2
// 876.436 us; speedup vs baseline: 1.8943x; 1.8943x over previous
//
#include <hip/hip_runtime.h>
#include <math.h>

#define TMASK 524287   // 2^19 - 1
#define PM0 455773     // 73856093 % 2^19
#define PM1 475295     // 19349663 % 2^19
#define PM2 130999     // 83492791 % 2^19

typedef __attribute__((ext_vector_type(8))) short bf16x8;
typedef __attribute__((ext_vector_type(4))) float f32x4;

// Transposed-bf16 weight buffer layout in d_ws (element offsets):
#define OFF_W0   0       // [128][64]   (K=52  pad 64)
#define OFF_W1   8192    // [128][128]
#define OFF_W2   24576   // [128][192]  (K=180 pad 192)
#define OFF_W3   49152   // [128][128]
#define OFF_E    65536   // [64][128]
#define OFF_M    73728   // [64][128]
#define OFF_P    81920   // [32][128]
#define OFF_MAT  86016   // [64][128]
#define OFF_S    94208   // [64][128]
#define WT_TOTAL 102400  // bf16 elements = 200 KiB

struct Params {
  const float* x; const float* freq; const float* tables;
  const float* b0; const float* b1; const float* b2; const float* b3;
  const float* e_b1; const float* e_w2; const float* e_b2; const float* e_g; const float* e_be;
  const float* m_b1; const float* m_w2; const float* m_b2; const float* m_g; const float* m_be;
  const float* p_b1; const float* p_w2; const float* p_b2;
  const float* mat_b1; const float* mat_w2; const float* mat_b2;
  const float* s_b1; const float* s_w2; const float* s_b2;
  const short* wt;
  float* out;
  int N;
  int res[16];
};

struct PrepParams {
  const float* src[9];
  int end[9];    // exclusive end offset (elements) of each region
  int Nsrc[9];   // src minor dim (= #output channels)
  int Ksrc[9];   // src major dim (= input K)
  int Kpad[9];
  short* wt;
};

__device__ __forceinline__ short f2bf(float f){
  union { float f; unsigned u; } v; v.f = f;
  unsigned r = v.u + 0x7fffu + ((v.u >> 16) & 1u);   // RNE
  return (short)(r >> 16);
}
__device__ __forceinline__ float sigmoid_(float v){ return 1.f/(1.f + expf(-v)); }

// ---------------- weight transpose+bf16 prep (runs every launch; ws is re-poisoned)
__global__ __launch_bounds__(256)
void prep_weights(PrepParams P)
{
  int id = blockIdx.x*256 + threadIdx.x;
  if (id >= WT_TOTAL) return;
  int r = 0, base = 0;
  #pragma unroll
  for (int i = 0; i < 9; ++i) { if (id >= P.end[i]) { r = i+1; base = P.end[i]; } }
  const int rel = id - base;
  const int kp = P.Kpad[r];
  const int n = rel / kp;
  const int k = rel - n*kp;
  float v = 0.f;
  if (k < P.Ksrc[r]) v = P.src[r][k * P.Nsrc[r] + n];
  P.wt[id] = f2bf(v);
}

// acc[NT] += A[16 x KC*32] @ Wt^T tiles. A: LDS bf16, row stride lda (elems), rows are the
// wave's 16 points. Wt: global bf16 [n][kpad] (transposed), kwoff = k offset into wt rows.
template<int NT, int KC>
__device__ __forceinline__ void mfma_acc(f32x4* acc, const short* A, int lda,
                                         const short* __restrict__ wt, int kpad, int kwoff,
                                         int lane)
{
  const int n0 = lane & 15, q = lane >> 4;
  const short* Ap = A + n0*lda + q*8;                 // A[m=lane&15][k=quad*8+j]
  const short* Bp = wt + n0*kpad + kwoff + q*8;       // B[k=quad*8+j][n=lane&15]
  #pragma unroll
  for (int kc = 0; kc < KC; ++kc) {
    bf16x8 a = *(const bf16x8*)(Ap + kc*32);
    #pragma unroll
    for (int nt = 0; nt < NT; ++nt) {
      bf16x8 b = *(const bf16x8*)(Bp + nt*16*kpad + kc*32);
      acc[nt] = __builtin_amdgcn_mfma_f32_16x16x32_bf16(a, b, acc[nt], 0, 0, 0);
    }
  }
}

// C layout: col = lane&15, row = (lane>>4)*4 + reg  (HW-verified m89/m91)
template<int NT, bool RELU>
__device__ __forceinline__ void epi_bf16(const f32x4* acc, const float* __restrict__ bias,
                                         short* out, int ldo, int lane)
{
  const int n0 = lane & 15, q = lane >> 4;
  #pragma unroll
  for (int nt = 0; nt < NT; ++nt) {
    const float bv = bias[nt*16 + n0];
    #pragma unroll
    for (int r = 0; r < 4; ++r) {
      float v = acc[nt][r] + bv;
      if (RELU) v = fmaxf(v, 0.f);
      out[(q*4 + r)*ldo + nt*16 + n0] = f2bf(v);
    }
  }
}

template<int NT, bool RELU>
__device__ __forceinline__ void epi_f32(const f32x4* acc, const float* __restrict__ bias,
                                        float* out, int ldo, int lane)
{
  const int n0 = lane & 15, q = lane >> 4;
  #pragma unroll
  for (int nt = 0; nt < NT; ++nt) {
    const float bv = bias[nt*16 + n0];
    #pragma unroll
    for (int r = 0; r < 4; ++r) {
      float v = acc[nt][r] + bv;
      if (RELU) v = fmaxf(v, 0.f);
      out[(q*4 + r)*ldo + nt*16 + n0] = v;
    }
  }
}

// per-point small second layer: optional LN (pre-relu), relu, @ W2[K2,OC2] + b2, optional tanh
template<int OC2, int K2, bool LN, bool TANH>
__device__ __forceinline__ void head_small(int tid, const float* headF,
    const float* __restrict__ g, const float* __restrict__ be,
    const float* __restrict__ W2, const float* __restrict__ b2,
    float* res2, int slot)
{
  if (tid < 64) {
    const float* row = headF + tid*69;
    float mn = 0.f, iv = 1.f;
    if constexpr (LN) {
      float s = 0.f;
      for (int k = 0; k < K2; ++k) s += row[k];
      mn = s * (1.f/K2);
      float v = 0.f;
      for (int k = 0; k < K2; ++k) { const float d = row[k]-mn; v = fmaf(d,d,v); }
      iv = 1.f / sqrtf(v*(1.f/K2) + 1e-5f);
    }
    float acc[OC2];
    #pragma unroll
    for (int j = 0; j < OC2; ++j) acc[j] = b2[j];
    for (int k = 0; k < K2; ++k) {
      float x = row[k];
      if constexpr (LN) x = (x - mn)*iv*g[k] + be[k];
      x = fmaxf(x, 0.f);   // idempotent for pre-relu'd non-LN heads
      #pragma unroll
      for (int j = 0; j < OC2; ++j) acc[j] = fmaf(x, W2[k*OC2 + j], acc[j]);
    }
    #pragma unroll
    for (int j = 0; j < OC2; ++j)
      res2[tid*20 + slot + j] = TANH ? tanhf(acc[j]) : acc[j];
  }
}

// LDS layout (bytes): featB bf16[64][72] @0 (9216) | region2 @9216 (17664):
//   hA bf16[64][136] (17408) aliased by headF f32[64][69] (17664) | hB bf16[64][136] @26880 (17408)
// res2 f32[64][20] aliases featB. Total 44288 B -> 3 blocks/CU.
__global__ __launch_bounds__(256, 3)
void em_nerf_mfma(Params P)
{
  __shared__ __align__(16) char smem[44288];
  short* featB = (short*)smem;
  short* hA    = (short*)(smem + 9216);
  short* hB    = (short*)(smem + 9216 + 17664);
  float* headF = (float*)(smem + 9216);
  float* res2  = (float*)smem;
  __shared__ int s_res[16];

  const int tid = threadIdx.x;
  if (tid == 0) {
    #pragma unroll
    for (int i = 0; i < 16; ++i) s_res[i] = P.res[i];
  }
  __syncthreads();

  // ---------------- encode: 64 points, 4 levels per thread-group
  {
    const int p = tid & 63;
    const int g = tid >> 6;            // 0..3, 4 levels each
    int gp = blockIdx.x*64 + p;
    if (gp >= P.N) gp = P.N - 1;
    const float xs0 = fminf(fmaxf(P.x[gp*3+0], 0.f), 1.f);
    const float xs1 = fminf(fmaxf(P.x[gp*3+1], 0.f), 1.f);
    const float xs2 = fminf(fmaxf(P.x[gp*3+2], 0.f), 1.f);
    #pragma unroll
    for (int j = 0; j < 4; ++j) {
      const int l = g*4 + j;
      const int res = s_res[l];
      const float rf = (float)(res-1);
      const float s0 = xs0*rf, s1 = xs1*rf, s2 = xs2*rf;
      int f0i = (int)s0; if (f0i > res-1) f0i = res-1;
      int f1i = (int)s1; if (f1i > res-1) f1i = res-1;
      int f2i = (int)s2; if (f2i > res-1) f2i = res-1;
      const float w0 = s0 - (float)f0i;
      const float w1 = s1 - (float)f1i;
      const float w2 = s2 - (float)f2i;
      int c0i = f0i+1; if (c0i > res-1) c0i = res-1;
      int c1i = f1i+1; if (c1i > res-1) c1i = res-1;
      int c2i = f2i+1; if (c2i > res-1) c2i = res-1;
      const int hx0 = (f0i*PM0) & TMASK, hx1 = (c0i*PM0) & TMASK;
      const int hy0 = (f1i*PM1) & TMASK, hy1 = (c1i*PM1) & TMASK;
      const int hz0 = (f2i*PM2) & TMASK, hz1 = (c2i*PM2) & TMASK;
      const float* tp = P.tables + ((size_t)l << 20);
      float a0 = 0.f, a1 = 0.f;
      #pragma unroll
      for (int cn = 0; cn < 8; ++cn) {
        const int bx = (cn>>2)&1, by = (cn>>1)&1, bz = cn&1;
        const int hh = ((bx?hx1:hx0) + (by?hy1:hy0) + (bz?hz1:hz0)) & TMASK;
        const float cw = (bx?w0:1.f-w0)*(by?w1:1.f-w1)*(bz?w2:1.f-w2);
        const float2 tv = *(const float2*)(tp + 2*hh);
        a0 = fmaf(cw, tv.x, a0);
        a1 = fmaf(cw, tv.y, a1);
      }
      featB[p*72 + 2*l]   = f2bf(a0);
      featB[p*72 + 2*l+1] = f2bf(a1);
    }
    if (g == 0) {
      float fr = P.freq[gp];
      fr = fminf(fmaxf(fr, 1e6f), 1e12f);
      const float nf = (log10f(fr) - 6.f) * (1.f/6.f);
      float a = 3.14159274101257324f * nf;
      #pragma unroll
      for (int i = 0; i < 10; ++i) {
        featB[p*72 + 32 + 2*i] = f2bf(sinf(a));
        featB[p*72 + 33 + 2*i] = f2bf(cosf(a));
        a = a * 2.f;
      }
    }
    if (g == 3) {
      #pragma unroll
      for (int k = 52; k < 64; ++k) featB[p*72 + k] = 0;   // concat zero-pad
    }
  }
  __syncthreads();

  const int lane = tid & 63, wave = tid >> 6;
  const short* A0 = featB + wave*16*72;
  const short* Ah = hA    + wave*16*136;
  const short* Bh = hB    + wave*16*136;

  // trunk L0: featB(64) -> hA
  { f32x4 acc[8] = {};
    mfma_acc<8,2>(acc, A0, 72, P.wt + OFF_W0, 64, 0, lane);
    epi_bf16<8,true>(acc, P.b0, hA + wave*16*136, 136, lane); }
  __syncthreads();
  // trunk L1: hA(128) -> hB
  { f32x4 acc[8] = {};
    mfma_acc<8,4>(acc, Ah, 136, P.wt + OFF_W1, 128, 0, lane);
    epi_bf16<8,true>(acc, P.b1, hB + wave*16*136, 136, lane); }
  __syncthreads();
  // trunk L2: [hB(128)|featB(64)] -> hA  (Wt2 rows 180..191 and featB cols 52..63 are zero)
  { f32x4 acc[8] = {};
    mfma_acc<8,4>(acc, Bh, 136, P.wt + OFF_W2, 192, 0, lane);
    mfma_acc<8,2>(acc, A0, 72,  P.wt + OFF_W2, 192, 128, lane);
    epi_bf16<8,true>(acc, P.b2, hA + wave*16*136, 136, lane); }
  __syncthreads();
  // trunk L3: hA(128) -> hB (= h for the heads)
  { f32x4 acc[8] = {};
    mfma_acc<8,4>(acc, Ah, 136, P.wt + OFF_W3, 128, 0, lane);
    epi_bf16<8,true>(acc, P.b3, hB + wave*16*136, 136, lane); }
  __syncthreads();

  // E head (LN+tanh) -> slots 0..2; raw (no relu) into headF
  { f32x4 acc[4] = {};
    mfma_acc<4,4>(acc, Bh, 136, P.wt + OFF_E, 128, 0, lane);
    epi_f32<4,false>(acc, P.e_b1, headF + wave*16*69, 69, lane); }
  __syncthreads();
  head_small<3,64,true,true>(tid, headF, P.e_g, P.e_be, P.e_w2, P.e_b2, res2, 0);
  __syncthreads();

  // B head (LN+tanh) -> slots 3..5
  { f32x4 acc[4] = {};
    mfma_acc<4,4>(acc, Bh, 136, P.wt + OFF_M, 128, 0, lane);
    epi_f32<4,false>(acc, P.m_b1, headF + wave*16*69, 69, lane); }
  __syncthreads();
  head_small<3,64,true,true>(tid, headF, P.m_g, P.m_be, P.m_w2, P.m_b2, res2, 3);
  __syncthreads();

  // phases head (32 hidden, relu in epi) -> slots 6..11
  { f32x4 acc[2] = {};
    mfma_acc<2,4>(acc, Bh, 136, P.wt + OFF_P, 128, 0, lane);
    epi_f32<2,true>(acc, P.p_b1, headF + wave*16*69, 69, lane); }
  __syncthreads();
  head_small<6,32,false,false>(tid, headF, nullptr, nullptr, P.p_w2, P.p_b2, res2, 6);
  __syncthreads();

  // material head -> slots 12..14
  { f32x4 acc[4] = {};
    mfma_acc<4,4>(acc, Bh, 136, P.wt + OFF_MAT, 128, 0, lane);
    epi_f32<4,true>(acc, P.mat_b1, headF + wave*16*69, 69, lane); }
  __syncthreads();
  head_small<3,64,false,false>(tid, headF, nullptr, nullptr, P.mat_w2, P.mat_b2, res2, 12);
  __syncthreads();

  // source head -> slots 15..18
  { f32x4 acc[4] = {};
    mfma_acc<4,4>(acc, Bh, 136, P.wt + OFF_S, 128, 0, lane);
    epi_f32<4,true>(acc, P.s_b1, headF + wave*16*69, 69, lane); }
  __syncthreads();
  head_small<4,64,false,false>(tid, headF, nullptr, nullptr, P.s_w2, P.s_b2, res2, 15);
  __syncthreads();

  // ---------------- final packing (TIME=0 -> cos(phases))
  if (tid < 64) {
    const int gp = blockIdx.x*64 + tid;
    if (gp < P.N) {
      const float* r = res2 + tid*20;
      float* o = P.out + (size_t)gp*13;
      o[0] = r[0]*cosf(r[6]);
      o[1] = r[1]*cosf(r[7]);
      o[2] = r[2]*cosf(r[8]);
      o[3] = r[3]*cosf(r[9]);
      o[4] = r[4]*cosf(r[10]);
      o[5] = r[5]*cosf(r[11]);
      o[6] = 1.f + sigmoid_(r[12])*10.f;
      o[7] = 1.f + sigmoid_(r[13])*2.f;
      o[8] = sigmoid_(r[14])*0.01f;
      o[9]  = r[15];
      o[10] = r[16];
      o[11] = r[17];
      o[12] = r[18];
    }
  }
}

extern "C" void kernel_launch(void* const* d_in, const int* in_sizes, int n_in,
                              void* d_out, int out_size, void* d_ws, size_t ws_size,
                              hipStream_t stream) {
  (void)n_in; (void)out_size; (void)ws_size;
  const float** in = (const float**)d_in;

  // prep: transpose+convert all first-layer weights to bf16 [n][kpad] in d_ws
  PrepParams PP;
  const float* srcs[9] = { in[3], in[5], in[7], in[9], in[11], in[15], in[19], in[23], in[27] };
  const int ends[9]  = { 8192, 24576, 49152, 65536, 73728, 81920, 86016, 94208, 102400 };
  const int nsrc[9]  = { 128, 128, 128, 128, 64, 64, 32, 64, 64 };
  const int ksrc[9]  = { 52, 128, 180, 128, 128, 128, 128, 128, 128 };
  const int kpad[9]  = { 64, 128, 192, 128, 128, 128, 128, 128, 128 };
  for (int i = 0; i < 9; ++i) { PP.src[i]=srcs[i]; PP.end[i]=ends[i]; PP.Nsrc[i]=nsrc[i]; PP.Ksrc[i]=ksrc[i]; PP.Kpad[i]=kpad[i]; }
  PP.wt = (short*)d_ws;
  hipLaunchKernelGGL(prep_weights, dim3((WT_TOTAL+255)/256), dim3(256), 0, stream, PP);

  Params P;
  P.x = in[0]; P.freq = in[1]; P.tables = in[2];
  P.b0 = in[4]; P.b1 = in[6]; P.b2 = in[8]; P.b3 = in[10];
  P.e_b1 = in[12]; P.e_w2 = in[13]; P.e_b2 = in[14];
  P.m_b1 = in[16]; P.m_w2 = in[17]; P.m_b2 = in[18];
  P.p_b1 = in[20]; P.p_w2 = in[21]; P.p_b2 = in[22];
  P.mat_b1 = in[24]; P.mat_w2 = in[25]; P.mat_b2 = in[26];
  P.s_b1 = in[28]; P.s_w2 = in[29]; P.s_b2 = in[30];
  P.e_g = in[31]; P.e_be = in[32]; P.m_g = in[33]; P.m_be = in[34];
  P.wt = (const short*)d_ws;
  P.out = (float*)d_out;
  P.N = in_sizes[0] / 3;

  // Python's module-level _RES, replicated with the same libm double math
  const double B = exp((log(512.0) - log(16.0)) / 15.0);
  for (int l = 0; l < 16; ++l) {
    double r = 16.0 * pow(B, (double)l);
    int ri = (int)r;
    if (ri > 512) ri = 512;
    P.res[l] = ri;
  }

  const int blocks = (P.N + 63) / 64;
  hipLaunchKernelGGL(em_nerf_mfma, dim3(blocks), dim3(256), 0, stream, P);
}